// Round 6
// baseline (172.625 us; speedup 1.0000x reference)
//
#include <hip/hip_runtime.h>

#define BLOCK 704   // 11 waves; exactly 2 blocks per row (1408 outputs/row)

// One thread per OUTPUT element. All region sizes (128/384/384/128/384) are
// multiples of 64, so every wave is region-uniform and every store
// instruction is a fully dense 256B run. Stores are nontemporal (never
// re-read, line-aligned). Reads of x1_1 are shared across regions of the
// same row; the XCD swizzle keeps both blocks of a row on one XCD's L2.
__global__ __launch_bounds__(BLOCK) void cg_tp_kernel(
    const float* __restrict__ x1,
    const float* __restrict__ x2,
    const float* __restrict__ wts,
    float* __restrict__ out,
    int N, int nblocks)
{
    constexpr float INV_SQRT3 = 0.57735026918962576451f;
    constexpr float INV_SQRT2 = 0.70710678118654752440f;

    // Bijective XCD-aware swizzle (m204): each XCD gets a contiguous logical
    // block range, so logical pairs (2r, 2r+1) share an XCD L2.
    int b   = blockIdx.x;
    int q   = nblocks >> 3, rr = nblocks & 7;
    int xcd = b & 7, idx = b >> 3;
    int Lb  = (xcd < rr ? xcd * (q + 1) : rr * (q + 1) + (xcd - rr) * q) + idx;

    int row = Lb >> 1;
    if (row >= N) return;
    int j = (Lb & 1) * BLOCK + (int)threadIdx.x;   // output index within row

    const float* x1r = x1  + (size_t)row * 512;
    const float* wr  = wts + (size_t)row * 640;
    float4 X2 = *(const float4*)(x2 + (size_t)row * 4);
    float s = X2.x, b0 = X2.y, b1 = X2.z, b2 = X2.w;

    float o;
    if (j < 128) {
        // out0: 0e x 0e -> 0e
        o = wr[j] * x1r[j] * s;
    } else if (j < 512) {
        // out1: 0e x 1o -> 1o
        unsigned e = (unsigned)(j - 128);
        unsigned u = e / 3u;
        unsigned c = e - 3u * u;
        float bb = (c == 0u) ? b0 : ((c == 1u) ? b1 : b2);
        o = wr[128 + u] * x1r[u] * bb;
    } else if (j < 896) {
        // out2: 1o x 0e -> 1o   (x1_1 read is perfectly dense here)
        unsigned e = (unsigned)(j - 512);
        unsigned u = e / 3u;
        o = wr[256 + u] * s * x1r[128 + e];
    } else if (j < 1024) {
        // out3: 1o . 1o -> 0e
        unsigned u = (unsigned)(j - 896);
        const float* a = x1r + 128 + 3 * u;
        float dot = a[0] * b0 + a[1] * b1 + a[2] * b2;
        o = wr[384 + u] * dot * INV_SQRT3;
    } else {
        // out4: 1o x 1o -> 1e (cross)
        unsigned e = (unsigned)(j - 1024);
        unsigned u = e / 3u;
        unsigned c = e - 3u * u;
        const float* a = x1r + 128 + 3 * u;
        float a0 = a[0], a1 = a[1], a2 = a[2];
        float cr0 = a1 * b2 - a2 * b1;
        float cr1 = a2 * b0 - a0 * b2;
        float cr2 = a0 * b1 - a1 * b0;
        float cc = (c == 0u) ? cr0 : ((c == 1u) ? cr1 : cr2);
        o = wr[512 + u] * cc * INV_SQRT2;
    }

    __builtin_nontemporal_store(o, out + (size_t)row * 1408 + j);
}

extern "C" void kernel_launch(void* const* d_in, const int* in_sizes, int n_in,
                              void* d_out, int out_size, void* d_ws, size_t ws_size,
                              hipStream_t stream)
{
    const float* x1  = (const float*)d_in[0];
    const float* x2  = (const float*)d_in[1];
    const float* wts = (const float*)d_in[2];
    float* out = (float*)d_out;

    int N = in_sizes[0] / 512;   // x1 is [N, 512]
    int nblocks = 2 * N;         // 2 blocks of 704 threads per row
    cg_tp_kernel<<<nblocks, BLOCK, 0, stream>>>(x1, x2, wts, out, N, nblocks);
}

// Round 7
// 78.258 us; speedup vs baseline: 2.2058x; 2.2058x over previous
//
#include <hip/hip_runtime.h>

#define MUL 128
#define BLOCK 256

// One thread per (row, channel). Same structure as the 97.8us R1 kernel
// (compiler merges the adjacent stride-3 dword accesses into dwordx3, so
// every wave-level access is dense), plus:
//  - nontemporal stores: output (never re-read) bypasses cache allocation,
//    so the L3 retains the inputs across graph replays (R6 profile showed
//    FETCH_SIZE = 113MB vs 231MB of inputs when NT stores were used).
//  - x2 loaded as a single float4 instead of 4 scalar dwords.
__global__ __launch_bounds__(BLOCK) void cg_tp_kernel(
    const float* __restrict__ x1,
    const float* __restrict__ x2,
    const float* __restrict__ wts,
    float* __restrict__ out,
    int N)
{
    constexpr float INV_SQRT3 = 0.57735026918962576451f;
    constexpr float INV_SQRT2 = 0.70710678118654752440f;

    int gid = blockIdx.x * blockDim.x + threadIdx.x;
    int total = N * MUL;
    if (gid >= total) return;

    int row = gid >> 7;   // gid / 128
    int u   = gid & 127;  // gid % 128

    const float* x1r  = x1  + (size_t)row * 512;
    const float* wr   = wts + (size_t)row * 640;
    float*       outr = out + (size_t)row * 1408;

    // x1 scalar (0e) channel
    float x10 = x1r[u];
    // x1 vector (1o) channel: 3 contiguous floats (merged to dwordx3)
    float a0 = x1r[128 + u * 3 + 0];
    float a1 = x1r[128 + u * 3 + 1];
    float a2 = x1r[128 + u * 3 + 2];
    // x2: one float4 (s, b0, b1, b2), wave-uniform per row
    float4 X2 = *(const float4*)(x2 + (size_t)row * 4);
    float s = X2.x, b0 = X2.y, b1 = X2.z, b2 = X2.w;
    // 5 per-instruction weights for this channel (each dense 256B/wave)
    float w0 = wr[0 * MUL + u];
    float w1 = wr[1 * MUL + u];
    float w2 = wr[2 * MUL + u];
    float w3 = wr[3 * MUL + u];
    float w4 = wr[4 * MUL + u];

    // out0: 0e x 0e -> 0e   [0, 128)
    __builtin_nontemporal_store(w0 * x10 * s, outr + u);

    // out1: 0e x 1o -> 1o   [128, 512)
    float w1x = w1 * x10;
    __builtin_nontemporal_store(w1x * b0, outr + 128 + 3 * u + 0);
    __builtin_nontemporal_store(w1x * b1, outr + 128 + 3 * u + 1);
    __builtin_nontemporal_store(w1x * b2, outr + 128 + 3 * u + 2);

    // out2: 1o x 0e -> 1o   [512, 896)
    float w2s = w2 * s;
    __builtin_nontemporal_store(w2s * a0, outr + 512 + 3 * u + 0);
    __builtin_nontemporal_store(w2s * a1, outr + 512 + 3 * u + 1);
    __builtin_nontemporal_store(w2s * a2, outr + 512 + 3 * u + 2);

    // out3: 1o . 1o -> 0e   [896, 1024)
    float dot = a0 * b0 + a1 * b1 + a2 * b2;
    __builtin_nontemporal_store(w3 * dot * INV_SQRT3, outr + 896 + u);

    // out4: 1o x 1o -> 1e (cross) [1024, 1408)
    float c0 = a1 * b2 - a2 * b1;
    float c1 = a2 * b0 - a0 * b2;
    float c2 = a0 * b1 - a1 * b0;
    float w4s = w4 * INV_SQRT2;
    __builtin_nontemporal_store(w4s * c0, outr + 1024 + 3 * u + 0);
    __builtin_nontemporal_store(w4s * c1, outr + 1024 + 3 * u + 1);
    __builtin_nontemporal_store(w4s * c2, outr + 1024 + 3 * u + 2);
}

extern "C" void kernel_launch(void* const* d_in, const int* in_sizes, int n_in,
                              void* d_out, int out_size, void* d_ws, size_t ws_size,
                              hipStream_t stream)
{
    const float* x1  = (const float*)d_in[0];
    const float* x2  = (const float*)d_in[1];
    const float* wts = (const float*)d_in[2];
    float* out = (float*)d_out;

    int N = in_sizes[0] / 512;  // x1 is [N, 512]
    int total = N * MUL;
    int grid = (total + BLOCK - 1) / BLOCK;
    cg_tp_kernel<<<grid, BLOCK, 0, stream>>>(x1, x2, wts, out, N);
}